// Round 6
// baseline (1296.500 us; speedup 1.0000x reference)
//
#include <hip/hip_runtime.h>
#include <stdint.h>

// ---------------------------------------------------------------------------
// ST-LSTM on MI355X.
//  K0 k_prep   : W_catT (2048x1536 bf16, T+XOR-swizzled for k_gemm LDS),
//                Wh_rearr (2048x512 bf16, col-reordered, LINEAR - consumed
//                into registers), zero h buf0 + sentinels.
//  K1 k_gather : A_cat (16384x1536 bf16, swizzled) = [x | q/3600 | sp/1000].
//  K2 k_gemm   : G (T,B,4H) bf16 = A_cat @ W_cat + bi.
//  K3 k_recur  : 64 active roles from 128 blocks (active iff bid%8<4):
//                r=bid%8 (16 batches), c=bid>>3 (32 h-dims). SENTINEL
//                protocol: publish h (plain+agent, untagged f32) -> vmcnt(0)
//                + barrier -> dual-store sent[r][c]=t+1. Consumers poll the
//                16-dword sentinel line only (64B/pass, kills the L2-BW
//                poll storm of R4/R5), then read h once. Wh B-fragments in
//                REGISTERS (loaded once). Sticky bounded fallback to agent
//                loads (= proven R2 path); monotonic sentinels => no hang.
//
// ws layout (bytes), total need = 126,091,520 (~120.2 MiB):
#define A_CAT_OFF  0ull                  // 16384*3072
#define WCT_OFF    50331648ull           // 2048*3072
#define WHR_OFF    56623104ull           // 2048*1024 (linear)
#define G_OFF      58720256ull           // 16384*2048*2
#define HBUF_OFF   125829120ull          // 2 bufs x 64 batches x 512 f32
#define SENT_OFF   126091264ull          // 4 r-groups x 16 u32 (64B lines)
#define WS_NEED    126091520ull

typedef short bf16x8 __attribute__((ext_vector_type(8)));
typedef float f32x4  __attribute__((ext_vector_type(4)));

__device__ __forceinline__ unsigned short f2bf(float f) {
  union { float f; uint32_t u; } v; v.f = f;
  uint32_t u = v.u;
  u += 0x7FFFu + ((u >> 16) & 1u);   // RNE
  return (unsigned short)(u >> 16);
}
__device__ __forceinline__ float bf2f(unsigned short h) {
  union { uint32_t u; float f; } v; v.u = ((uint32_t)h) << 16;
  return v.f;
}
__device__ __forceinline__ float u2f(uint32_t u) {
  union { uint32_t u; float f; } v; v.u = u; return v.f;
}
__device__ __forceinline__ uint32_t f2u(float f) {
  union { float f; uint32_t u; } v; v.f = f; return v.u;
}
__device__ __forceinline__ float fsigmoid(float x) { return 1.0f / (1.0f + __expf(-x)); }
__device__ __forceinline__ float ftanh(float x) {
  float e = __expf(2.0f * x);
  return 1.0f - 2.0f / (e + 1.0f);
}
__device__ __forceinline__ uint4 pack8(const unsigned short* v) {
  uint4 r;
  r.x = (uint32_t)v[0] | ((uint32_t)v[1] << 16);
  r.y = (uint32_t)v[2] | ((uint32_t)v[3] << 16);
  r.z = (uint32_t)v[4] | ((uint32_t)v[5] << 16);
  r.w = (uint32_t)v[6] | ((uint32_t)v[7] << 16);
  return r;
}

#define GLOAD_LDS16(GP, LP)                                                   \
  __builtin_amdgcn_global_load_lds(                                          \
      (const __attribute__((address_space(1))) uint32_t*)(GP),               \
      (__attribute__((address_space(3))) uint32_t*)(LP), 16, 0, 0)

// ---------------------------------------------------------------------- K0
__global__ __launch_bounds__(256) void k_prep(
    const float* __restrict__ Wi, const float* __restrict__ Wt,
    const float* __restrict__ Ws, const float* __restrict__ Wh,
    uint8_t* ws) {
  int id = blockIdx.x * 256 + threadIdx.x;
  if (id < 393216) {                       // W_catT: 2048 cols x 192 k-chunks
    int n  = id & 2047;
    int k0 = (id >> 11) << 3;
    unsigned short v[8];
#pragma unroll
    for (int j = 0; j < 8; ++j) {
      int k = k0 + j;
      float x;
      if (k < 512)       x = Wi[k * 2048 + n];
      else if (k < 1024) x = (n < 1536) ? Wt[(k - 512) * 1536 + n] : 0.0f;
      else               x = (n < 1536) ? Ws[(k - 1024) * 1536 + n] : 0.0f;
      v[j] = f2bf(x);
    }
    size_t off = WCT_OFF + (size_t)n * 3072 +
                 (size_t)(((uint32_t)k0 * 2u) ^ (((uint32_t)n & 7u) << 4));
    *(uint4*)(ws + off) = pack8(v);
  } else if (id < 524288) {                // Wh_rearr: LINEAR (reg-consumed)
    int id2 = id - 393216;
    int cc  = id2 & 2047;
    int k0  = (id2 >> 11) << 3;
    int col = ((cc >> 5) & 3) * 512 + (cc >> 7) * 32 + (cc & 31);
    unsigned short v[8];
#pragma unroll
    for (int j = 0; j < 8; ++j) v[j] = f2bf(Wh[(size_t)(k0 + j) * 2048 + col]);
    *(uint4*)(ws + WHR_OFF + (size_t)cc * 1024 + (size_t)k0 * 2) = pack8(v);
  } else if (id < 532480) {                // h buf0 = h_0 = 0.0f
    uint4 z; z.x = z.y = z.z = z.w = 0u;
    *(uint4*)(ws + HBUF_OFF + (size_t)(id - 524288) * 16) = z;
  } else if (id < 532496) {                // sentinels = 0 (h_0 ready)
    uint4 z; z.x = z.y = z.z = z.w = 0u;
    *(uint4*)(ws + SENT_OFF + (size_t)(id - 532480) * 16) = z;
  }
}

// ---------------------------------------------------------------------- K1
__global__ __launch_bounds__(192) void k_gather(
    const int* __restrict__ loc, const int* __restrict__ tdu,
    const int* __restrict__ tdl, const int* __restrict__ sdu,
    const int* __restrict__ sdl,
    const float* __restrict__ loc_emb, const float* __restrict__ tup,
    const float* __restrict__ tlo, const float* __restrict__ sup,
    const float* __restrict__ slo, uint8_t* ws) {
  int m  = blockIdx.x;        // row = b*256 + t
  int t  = m & 255;
  int k0 = threadIdx.x << 3;  // 192 chunks of 8
  float vals[8];
  if (k0 < 512) {
    const float* s = loc_emb + (size_t)loc[m] * 512 + k0;
#pragma unroll
    for (int j = 0; j < 8; ++j) vals[j] = s[j];
  } else if (k0 < 1024) {
    int e = k0 - 512;
    const float* a = tup + (size_t)tdu[m] * 512 + e;
    const float* b = tlo + (size_t)tdl[m] * 512 + e;
    float sc = (t > 0) ? (1.0f / 3600.0f) : 0.0f;
#pragma unroll
    for (int j = 0; j < 8; ++j) vals[j] = (a[j] + b[j]) * sc;
  } else {
    int e = k0 - 1024;
    const float* a = sup + (size_t)sdu[m] * 512 + e;
    const float* b = slo + (size_t)sdl[m] * 512 + e;
    float sc = (t > 0) ? (1.0f / 1000.0f) : 0.0f;
#pragma unroll
    for (int j = 0; j < 8; ++j) vals[j] = (a[j] + b[j]) * sc;
  }
  unsigned short v[8];
#pragma unroll
  for (int j = 0; j < 8; ++j) v[j] = f2bf(vals[j]);
  size_t off = A_CAT_OFF + (size_t)m * 3072 +
               (size_t)(((uint32_t)k0 * 2u) ^ (((uint32_t)m & 7u) << 4));
  *(uint4*)(ws + off) = pack8(v);
}

// ---------------------------------------------------------------------- K2
__global__ __launch_bounds__(256) void k_gemm(uint8_t* ws,
                                              const float* __restrict__ bi) {
  __shared__ uint8_t A_lds[16384];   // 128 rows x 64 k bf16 (swizzled content)
  __shared__ uint8_t B_lds[16384];   // 128 cols x 64 k bf16
  const uint8_t* Acat = ws + A_CAT_OFF;
  const uint8_t* Wct  = ws + WCT_OFF;
  uint8_t* Gp = ws + G_OFF;
  int tid = threadIdx.x;
  int lane = tid & 63, wave = tid >> 6;
  int wm = wave >> 1, wn = wave & 1;
  int tile_m = blockIdx.x >> 4, tile_n = blockIdx.x & 15;

  f32x4 acc[4][4];
#pragma unroll
  for (int m = 0; m < 4; ++m)
#pragma unroll
    for (int n = 0; n < 4; ++n) acc[m][n] = f32x4{0.f, 0.f, 0.f, 0.f};

  for (int kb = 0; kb < 1536; kb += 64) {
#pragma unroll
    for (int i = 0; i < 4; ++i) {
      int lidx = i * 256 + tid;
      int row = lidx >> 3, ch = lidx & 7;
      GLOAD_LDS16(Acat + (size_t)(tile_m * 128 + row) * 3072 + kb * 2 + ch * 16,
                  A_lds + (i * 256 + wave * 64) * 16);
    }
#pragma unroll
    for (int i = 0; i < 4; ++i) {
      int lidx = i * 256 + tid;
      int row = lidx >> 3, ch = lidx & 7;
      GLOAD_LDS16(Wct + (size_t)(tile_n * 128 + row) * 3072 + kb * 2 + ch * 16,
                  B_lds + (i * 256 + wave * 64) * 16);
    }
    __syncthreads();
#pragma unroll
    for (int kk = 0; kk < 2; ++kk) {
      int koff = kk * 64 + ((lane >> 4) << 4);
      bf16x8 af[4], bfr[4];
#pragma unroll
      for (int m = 0; m < 4; ++m) {
        int row = wm * 64 + m * 16 + (lane & 15);
        af[m] = *(const bf16x8*)(A_lds + row * 128 + (koff ^ ((row & 7) << 4)));
      }
#pragma unroll
      for (int n = 0; n < 4; ++n) {
        int row = wn * 64 + n * 16 + (lane & 15);
        bfr[n] = *(const bf16x8*)(B_lds + row * 128 + (koff ^ ((row & 7) << 4)));
      }
#pragma unroll
      for (int m = 0; m < 4; ++m)
#pragma unroll
        for (int n = 0; n < 4; ++n)
          acc[m][n] = __builtin_amdgcn_mfma_f32_16x16x32_bf16(af[m], bfr[n],
                                                              acc[m][n], 0, 0, 0);
    }
    __syncthreads();
  }
  // epilogue: + bias, bf16, scatter to G laid out (T, B, 4H)
  int lr = lane >> 4, lc = lane & 15;
#pragma unroll
  for (int n = 0; n < 4; ++n) {
    int gcol = tile_n * 128 + wn * 64 + n * 16 + lc;
    float bv = bi[gcol];
#pragma unroll
    for (int m = 0; m < 4; ++m) {
      int growb = tile_m * 128 + wm * 64 + m * 16 + lr * 4;
#pragma unroll
      for (int q = 0; q < 4; ++q) {
        int grow = growb + q;                      // = b*256 + t
        float v = acc[m][n][q] + bv;
        size_t gi = ((size_t)(grow & 255) * 64 + (size_t)(grow >> 8)) * 2048 + gcol;
        *(unsigned short*)(Gp + gi * 2) = f2bf(v);
      }
    }
  }
}

// ---------------------------------------------------------------------- K3
// 128 blocks x 512 threads, active iff bid%8<4 (64 roles). r=bid%8, c=bid>>3.
// 96 KB dummy dynamic LDS forces 1 block/CU (preserves R4-verified placement).
__global__ __launch_bounds__(512, 2) void k_recur(uint8_t* ws,
                                                  const int* __restrict__ vlen,
                                                  float* __restrict__ out) {
  int bid = blockIdx.x;
  if ((bid & 7) >= 4) return;
  int r = bid & 7, c = bid >> 3;

  extern __shared__ uint8_t smem[];
  uint8_t* h_lds = smem;                    // [16][512] bf16 swizzled, 16384 B
  float*   tmp   = (float*)(smem + 16384);  // [16][132] f32, 8448 B

  int tid = threadIdx.x;
  int lane = tid & 63, wave = tid >> 6;

  const uint8_t* Gp  = ws + G_OFF;
  const uint8_t* Whr = ws + WHR_OFF;
  uint32_t* sent = (uint32_t*)(ws + SENT_OFF) + r * 16;

  // ---- Wh B-fragments -> registers (ONCE; Wh is time-invariant)
  bf16x8 Bfrag[16];
  {
    int cc = c * 128 + wave * 16 + (lane & 15);
    const uint8_t* wb = Whr + (size_t)cc * 1024 + ((lane >> 4) << 4);
#pragma unroll
    for (int kk = 0; kk < 16; ++kk)
      Bfrag[kk] = *(const bf16x8*)(wb + kk * 64);
  }

  int gb = tid >> 5, d = tid & 31;         // gate mapping: (batch gb, dim d)
  int gbatch = r * 16 + gb;
  int vl = vlen[gbatch];
  float cr = 0.0f, hprev = 0.0f, cprev = 0.0f;
  bool fb = false;                         // sticky fallback (agent loads)

  int hb_b = 2 * wave + (lane >> 5);       // h-read: batch
  int hb_byte = (lane & 31) * 64;          // h-read: byte off in f32 row

  float* outH  = out;
  float* outLH = out + 8388608;
  float* outLC = out + 8421376;

  __syncthreads();

  for (int t = 0; t < 256; ++t) {
    // ---- poll sentinel line: all sent[r][*] >= t (64 B/pass)
    {
      const uint32_t* sp = sent + (lane & 15);
      int passes = 0;
      for (;;) {
        uint32_t sv;
        if (!fb) {
          asm volatile("global_load_dword %0, %1, off sc0\n\t"
                       "s_waitcnt vmcnt(0)"
                       : "=v"(sv) : "v"(sp) : "memory");
          __builtin_amdgcn_sched_barrier(0);
        } else {
          sv = __hip_atomic_load(sp, __ATOMIC_RELAXED, __HIP_MEMORY_SCOPE_AGENT);
        }
        if (__ballot(sv >= (uint32_t)t) == ~0ULL) break;
        if (++passes > 64) fb = true;      // bounded: degrade, never hang
      }
    }
    // ---- read h_t slice ONCE (validity guaranteed: producer ack'd h
    //      stores, plain+agent, before storing its sentinel)
    uint64_t x[8];
    {
      const uint8_t* hb = ws + HBUF_OFF + (size_t)(t & 1) * 131072 +
                          (size_t)(r * 16 + hb_b) * 2048 + hb_byte;
      if (!fb) {
#pragma unroll
        for (int i = 0; i < 8; ++i) {
          const void* p = hb + i * 8;
          asm volatile("global_load_dwordx2 %0, %1, off sc0"
                       : "=v"(x[i]) : "v"(p) : "memory");
        }
        asm volatile("s_waitcnt vmcnt(0)" ::: "memory");
        __builtin_amdgcn_sched_barrier(0);
      } else {
#pragma unroll
        for (int i = 0; i < 8; ++i)
          x[i] = __hip_atomic_load((const uint64_t*)(hb + i * 8),
                                   __ATOMIC_RELAXED, __HIP_MEMORY_SCOPE_AGENT);
      }
    }
    // ---- G loads for THIS step (HBM; consumed ~1 phase later in gates)
    unsigned short gv0, gv1, gv2, gv3;
    {
      const uint8_t* gp = Gp + (size_t)(t * 64 + gbatch) * 4096 +
                          (size_t)(c * 64 + d * 2);
      gv0 = *(const unsigned short*)(gp);
      gv1 = *(const unsigned short*)(gp + 1024);
      gv2 = *(const unsigned short*)(gp + 2048);
      gv3 = *(const unsigned short*)(gp + 3072);
    }
    // ---- delayed outputs for step t-1 (store-acks overlap MFMA phase)
    if (t > 0) {
      outH[((size_t)gbatch * 256 + (size_t)(t - 1)) * 512 + (size_t)(c * 32 + d)] = hprev;
      if (t - 1 == vl - 1) {
        size_t lb = (size_t)gbatch * 512 + (size_t)(c * 32 + d);
        outLH[lb] = hprev;
        outLC[lb] = cprev;
      }
    }
    // ---- cvt f32->bf16, write swizzled h_lds
    {
      uint32_t w[8];
#pragma unroll
      for (int i = 0; i < 8; ++i) {
        uint32_t lo = (uint32_t)x[i], hi = (uint32_t)(x[i] >> 32);
        w[i] = (uint32_t)f2bf(u2f(lo)) | ((uint32_t)f2bf(u2f(hi)) << 16);
      }
      int base = hb_b * 1024 + (lane & 31) * 32;
      int swz = (hb_b & 7) << 4;
      uint4 v0; v0.x = w[0]; v0.y = w[1]; v0.z = w[2]; v0.w = w[3];
      uint4 v1; v1.x = w[4]; v1.y = w[5]; v1.z = w[6]; v1.w = w[7];
      *(uint4*)(h_lds + (base ^ swz)) = v0;
      *(uint4*)(h_lds + ((base + 16) ^ swz)) = v1;
    }
    __syncthreads();                               // B1

    // ---- MFMA: tmp(16 x wave's 16 cols) = h(16x512) @ Wh_regs
    f32x4 acc = f32x4{0.f, 0.f, 0.f, 0.f};
    {
      int lrow = lane & 15;
      int g16 = (lane >> 4) << 4;
      int aswz = (lrow & 7) << 4;
#pragma unroll
      for (int kk = 0; kk < 16; ++kk) {
        bf16x8 a = *(const bf16x8*)(h_lds + lrow * 1024 + ((kk * 64 + g16) ^ aswz));
        acc = __builtin_amdgcn_mfma_f32_16x16x32_bf16(a, Bfrag[kk], acc, 0, 0, 0);
      }
    }
    {  // D layout: col=lane&15, row(batch)=(lane>>4)*4+q; stride 132 (2-way)
      int colb = wave * 16 + (lane & 15);
      int rowd = (lane >> 4) << 2;
#pragma unroll
      for (int q = 0; q < 4; ++q)
        tmp[(rowd + q) * 132 + colb] = acc[q];
    }
    __syncthreads();                               // B2

    // ---- gates
    float hval, cval;
    {
      int tb = gb * 132 + d;
      float ip = tmp[tb]      + bf2f(gv0);
      float fp = tmp[tb + 32] + bf2f(gv1);
      float op = tmp[tb + 64] + bf2f(gv2);
      float gp = tmp[tb + 96] + bf2f(gv3);
      float ig = fsigmoid(ip), fg = fsigmoid(fp), og = fsigmoid(op);
      float gt = ftanh(gp);
      cval = fg * cr + ig * gt;
      cr = cval;
      hval = og * ftanh(cval);
    }
    // ---- publish h_{t+1}: plain (same-XCD L2) + agent (IC, for fallback)
    {
      uint32_t hw = f2u(hval);
      uint32_t* pub = (uint32_t*)(ws + HBUF_OFF + (size_t)((t + 1) & 1) * 131072 +
                                  (size_t)gbatch * 2048 + (size_t)(c * 32 + d) * 4);
      asm volatile("global_store_dword %0, %1, off" :: "v"(pub), "v"(hw) : "memory");
      __hip_atomic_store(pub, hw, __ATOMIC_RELAXED, __HIP_MEMORY_SCOPE_AGENT);
    }
    hprev = hval; cprev = cval;
    asm volatile("s_waitcnt vmcnt(0)" ::: "memory");  // h stores ack'd (wave)
    __syncthreads();                               // B3 (all waves ack'd)
    if (tid == 0) {                                // sentinel: h_{t+1} ready
      uint32_t sval = (uint32_t)(t + 1);
      uint32_t* sc = sent + c;
      asm volatile("global_store_dword %0, %1, off" :: "v"(sc), "v"(sval) : "memory");
      __hip_atomic_store(sc, sval, __ATOMIC_RELAXED, __HIP_MEMORY_SCOPE_AGENT);
    }
  }
  // ---- final delayed outputs (t = 255)
  outH[((size_t)gbatch * 256 + 255) * 512 + (size_t)(c * 32 + d)] = hprev;
  if (vl == 256) {
    size_t lb = (size_t)gbatch * 512 + (size_t)(c * 32 + d);
    outLH[lb] = hprev;
    outLC[lb] = cprev;
  }
}

// ---------------------------------------------------------------------------
extern "C" void kernel_launch(void* const* d_in, const int* in_sizes, int n_in,
                              void* d_out, int out_size, void* d_ws, size_t ws_size,
                              hipStream_t stream) {
  const int*   loc     = (const int*)d_in[0];
  const int*   tdu     = (const int*)d_in[1];
  const int*   tdl     = (const int*)d_in[2];
  const int*   sdu     = (const int*)d_in[3];
  const int*   sdl     = (const int*)d_in[4];
  const int*   vlen    = (const int*)d_in[5];
  const float* loc_emb = (const float*)d_in[6];
  const float* tup     = (const float*)d_in[7];
  const float* tlo     = (const float*)d_in[8];
  const float* sup     = (const float*)d_in[9];
  const float* slo     = (const float*)d_in[10];
  const float* Wt      = (const float*)d_in[11];
  const float* Ws      = (const float*)d_in[12];
  const float* Wi      = (const float*)d_in[13];
  const float* bi      = (const float*)d_in[14];
  const float* Wh      = (const float*)d_in[15];
  uint8_t* ws = (uint8_t*)d_ws;
  float* out = (float*)d_out;

  if (ws_size < WS_NEED) return;  // need ~120.2 MiB scratch

  (void)hipFuncSetAttribute((const void*)k_recur,
                            hipFuncAttributeMaxDynamicSharedMemorySize, 98304);

  k_prep  <<<2081, 256, 0, stream>>>(Wi, Wt, Ws, Wh, ws);
  k_gather<<<16384, 192, 0, stream>>>(loc, tdu, tdl, sdu, sdl,
                                      loc_emb, tup, tlo, sup, slo, ws);
  k_gemm  <<<2048, 256, 0, stream>>>(ws, bi);
  k_recur <<<128, 512, 98304, stream>>>(ws, vlen, out);
}